// Round 4
// baseline (270.851 us; speedup 1.0000x reference)
//
#include <hip/hip_runtime.h>

#define GIOU_GRID    1024
#define GIOU_THREADS 256
#define UNROLL       4

typedef float v4f __attribute__((ext_vector_type(4)));

__device__ __forceinline__ float giou_loss(v4f p, v4f t) {
    float area_p = (p.z - p.x) * (p.w - p.y);
    float area_t = (t.z - t.x) * (t.w - t.y);

    float iw = fmaxf(fminf(p.z, t.z) - fmaxf(p.x, t.x), 0.0f);
    float ih = fmaxf(fminf(p.w, t.w) - fmaxf(p.y, t.y), 0.0f);
    float inter = iw * ih;
    float uni   = area_p + area_t - inter;

    float ew = fmaxf(p.z, t.z) - fminf(p.x, t.x);
    float eh = fmaxf(p.w, t.w) - fminf(p.y, t.y);
    float enclose = ew * eh;

    // 1 - giou = 2 - inter/union - union/enclose  (fast rcp: err ~1e-5 << 2.75e-2 threshold)
    return 2.0f - inter * __builtin_amdgcn_rcpf(uni)
                - uni   * __builtin_amdgcn_rcpf(enclose);
}

// R4: PLAIN loads (nt removed), keeping R3's contiguous per-block chunks.
// Theory: the old 2.6 TB/s plain-load plateau was an L1 SET-conflict artifact
// of the grid-stride pattern (4 MB batch stride -> all 8 loads in one L1 set,
// per-set miss queue serializes). Chunked batches span contiguous 16 KB ->
// sets spread evenly -> plain loads should stream at full rate, and nt's
// L2-dealloc/streaming-class penalty goes away.
__global__ __launch_bounds__(GIOU_THREADS) void giou_partial_kernel(
        const v4f* __restrict__ pred,
        const v4f* __restrict__ targ,
        double* __restrict__ partials,
        int n) {
    // balanced chunk split: blocks [0,r) get q+1 elems, rest get q
    int b = blockIdx.x;
    int q = n / GIOU_GRID;
    int r = n - q * GIOU_GRID;
    int start = b * q + (b < r ? b : r);
    int end   = start + q + (b < r ? 1 : 0);

    float sum = 0.0f;
    int i = start + threadIdx.x;

    // Main loop: 8 dwordx4 loads in flight, all within a contiguous 2x16 KB window.
    for (; i + (UNROLL - 1) * GIOU_THREADS < end; i += UNROLL * GIOU_THREADS) {
        v4f p[UNROLL], t[UNROLL];
        #pragma unroll
        for (int u = 0; u < UNROLL; ++u) p[u] = pred[i + u * GIOU_THREADS];
        #pragma unroll
        for (int u = 0; u < UNROLL; ++u) t[u] = targ[i + u * GIOU_THREADS];
        #pragma unroll
        for (int u = 0; u < UNROLL; ++u) sum += giou_loss(p[u], t[u]);
    }
    // 2-wide tail step
    for (; i + GIOU_THREADS < end; i += 2 * GIOU_THREADS) {
        v4f p0 = pred[i];
        v4f p1 = pred[i + GIOU_THREADS];
        v4f t0 = targ[i];
        v4f t1 = targ[i + GIOU_THREADS];
        sum += giou_loss(p0, t0);
        sum += giou_loss(p1, t1);
    }
    // final scalar tail
    for (; i < end; i += GIOU_THREADS)
        sum += giou_loss(pred[i], targ[i]);

    // wave-64 butterfly reduction
    #pragma unroll
    for (int off = 32; off > 0; off >>= 1)
        sum += __shfl_down(sum, off, 64);

    __shared__ float wave_sums[GIOU_THREADS / 64];
    int lane = threadIdx.x & 63;
    int wave = threadIdx.x >> 6;
    if (lane == 0) wave_sums[wave] = sum;
    __syncthreads();

    if (threadIdx.x == 0) {
        double bsum = 0.0;
        #pragma unroll
        for (int w = 0; w < GIOU_THREADS / 64; ++w) bsum += (double)wave_sums[w];
        partials[blockIdx.x] = bsum;   // every block writes unconditionally -> no memset needed
    }
}

__global__ __launch_bounds__(GIOU_THREADS) void giou_final_kernel(
        const double* __restrict__ partials,
        float* __restrict__ out,
        int nblocks, int n) {
    double s = 0.0;
    for (int i = threadIdx.x; i < nblocks; i += blockDim.x)
        s += partials[i];

    #pragma unroll
    for (int off = 32; off > 0; off >>= 1)
        s += __shfl_down(s, off, 64);

    __shared__ double wave_sums[GIOU_THREADS / 64];
    int lane = threadIdx.x & 63;
    int wave = threadIdx.x >> 6;
    if (lane == 0) wave_sums[wave] = s;
    __syncthreads();

    if (threadIdx.x == 0) {
        double tot = 0.0;
        #pragma unroll
        for (int w = 0; w < GIOU_THREADS / 64; ++w) tot += wave_sums[w];
        out[0] = (float)(tot / (double)n);
    }
}

extern "C" void kernel_launch(void* const* d_in, const int* in_sizes, int n_in,
                              void* d_out, int out_size, void* d_ws, size_t ws_size,
                              hipStream_t stream) {
    const v4f* pred = (const v4f*)d_in[0];
    const v4f* targ = (const v4f*)d_in[1];
    float* out = (float*)d_out;
    double* partials = (double*)d_ws;   // GIOU_GRID doubles = 8 KB

    int n = in_sizes[0] / 4;            // number of boxes (flat count is n*4)

    giou_partial_kernel<<<GIOU_GRID, GIOU_THREADS, 0, stream>>>(pred, targ, partials, n);
    giou_final_kernel<<<1, GIOU_THREADS, 0, stream>>>(partials, out, GIOU_GRID, n);
}

// Round 5
// 242.970 us; speedup vs baseline: 1.1148x; 1.1148x over previous
//
#include <hip/hip_runtime.h>

#define GIOU_GRID    1024
#define GIOU_THREADS 256
#define UNROLL       4

typedef float v4f __attribute__((ext_vector_type(4)));

__device__ __forceinline__ float giou_loss(v4f p, v4f t) {
    float area_p = (p.z - p.x) * (p.w - p.y);
    float area_t = (t.z - t.x) * (t.w - t.y);

    float iw = fmaxf(fminf(p.z, t.z) - fmaxf(p.x, t.x), 0.0f);
    float ih = fmaxf(fminf(p.w, t.w) - fmaxf(p.y, t.y), 0.0f);
    float inter = iw * ih;
    float uni   = area_p + area_t - inter;

    float ew = fmaxf(p.z, t.z) - fminf(p.x, t.x);
    float eh = fmaxf(p.w, t.w) - fminf(p.y, t.y);
    float enclose = ew * eh;

    // 1 - giou = 2 - inter/union - union/enclose  (fast rcp: err ~1e-5 << 2.75e-2 threshold)
    return 2.0f - inter * __builtin_amdgcn_rcpf(uni)
                - uni   * __builtin_amdgcn_rcpf(enclose);
}

// R5: explicit 2-stage register pipeline (named A/B batches, no copies) on top
// of R3's nt+chunked base. R4 evidence: plain-load variant had VGPR_Count=32 ->
// compiler issues loads just-in-time (1-2 outstanding/wave, full vmcnt drain
// per iter), "8 in flight" was fiction. Pipeline forces both batches live
// (~100 VGPR, still 4 waves/SIMD at our grid-limited residency) and turns the
// drain into a counted vmcnt overlapped with the next batch's issue.
__global__ __launch_bounds__(GIOU_THREADS) void giou_partial_kernel(
        const v4f* __restrict__ pred,
        const v4f* __restrict__ targ,
        double* __restrict__ partials,
        int n) {
    // balanced contiguous chunk per block: blocks [0,r) get q+1 elems, rest get q
    int blk = blockIdx.x;
    int q = n / GIOU_GRID;
    int r = n - q * GIOU_GRID;
    int start = blk * q + (blk < r ? blk : r);
    int end   = start + q + (blk < r ? 1 : 0);

    const int T    = GIOU_THREADS;
    const int step = UNROLL * T;

    int i0  = start + threadIdx.x;
    int cnt = (end > i0) ? (end - i0 + T - 1) / T : 0;   // this lane's element count
    int nb  = cnt / UNROLL;                              // full UNROLL-batches

    float sum = 0.0f;

    v4f pA[UNROLL], tA[UNROLL], pB[UNROLL], tB[UNROLL];

#define LOAD(P, Tt, base)                                                        \
    do {                                                                         \
        _Pragma("unroll")                                                        \
        for (int u = 0; u < UNROLL; ++u) P[u]  = __builtin_nontemporal_load(&pred[(base) + u * T]); \
        _Pragma("unroll")                                                        \
        for (int u = 0; u < UNROLL; ++u) Tt[u] = __builtin_nontemporal_load(&targ[(base) + u * T]); \
    } while (0)

#define COMPUTE(P, Tt)                                                           \
    do {                                                                         \
        _Pragma("unroll")                                                        \
        for (int u = 0; u < UNROLL; ++u) sum += giou_loss(P[u], Tt[u]);          \
    } while (0)

    int i = i0;
    int b = 0;
    if (nb > 0) LOAD(pA, tA, i);                 // prologue: batch 0 -> A
    while (b + 2 <= nb) {
        LOAD(pB, tB, i + step);                  // issue B while A in flight
        __builtin_amdgcn_sched_barrier(0);       // keep loads clustered before compute
        COMPUTE(pA, tA);                         // waits counted vmcnt (B outstanding)
        if (b + 2 < nb) LOAD(pA, tA, i + 2 * step);
        __builtin_amdgcn_sched_barrier(0);
        COMPUTE(pB, tB);
        i += 2 * step;
        b += 2;
    }
    if (b < nb) COMPUTE(pA, tA);                 // odd leftover batch (already loaded)

#undef LOAD
#undef COMPUTE

    // scalar remainder: elements beyond the full batches
    int ir = i0 + nb * step;
    for (int k = nb * UNROLL; k < cnt; ++k, ir += T)
        sum += giou_loss(__builtin_nontemporal_load(&pred[ir]),
                         __builtin_nontemporal_load(&targ[ir]));

    // wave-64 butterfly reduction
    #pragma unroll
    for (int off = 32; off > 0; off >>= 1)
        sum += __shfl_down(sum, off, 64);

    __shared__ float wave_sums[GIOU_THREADS / 64];
    int lane = threadIdx.x & 63;
    int wave = threadIdx.x >> 6;
    if (lane == 0) wave_sums[wave] = sum;
    __syncthreads();

    if (threadIdx.x == 0) {
        double bsum = 0.0;
        #pragma unroll
        for (int w = 0; w < GIOU_THREADS / 64; ++w) bsum += (double)wave_sums[w];
        partials[blockIdx.x] = bsum;   // every block writes unconditionally -> no memset needed
    }
}

__global__ __launch_bounds__(GIOU_THREADS) void giou_final_kernel(
        const double* __restrict__ partials,
        float* __restrict__ out,
        int nblocks, int n) {
    double s = 0.0;
    for (int i = threadIdx.x; i < nblocks; i += blockDim.x)
        s += partials[i];

    #pragma unroll
    for (int off = 32; off > 0; off >>= 1)
        s += __shfl_down(s, off, 64);

    __shared__ double wave_sums[GIOU_THREADS / 64];
    int lane = threadIdx.x & 63;
    int wave = threadIdx.x >> 6;
    if (lane == 0) wave_sums[wave] = s;
    __syncthreads();

    if (threadIdx.x == 0) {
        double tot = 0.0;
        #pragma unroll
        for (int w = 0; w < GIOU_THREADS / 64; ++w) tot += wave_sums[w];
        out[0] = (float)(tot / (double)n);
    }
}

extern "C" void kernel_launch(void* const* d_in, const int* in_sizes, int n_in,
                              void* d_out, int out_size, void* d_ws, size_t ws_size,
                              hipStream_t stream) {
    const v4f* pred = (const v4f*)d_in[0];
    const v4f* targ = (const v4f*)d_in[1];
    float* out = (float*)d_out;
    double* partials = (double*)d_ws;   // GIOU_GRID doubles = 8 KB

    int n = in_sizes[0] / 4;            // number of boxes (flat count is n*4)

    giou_partial_kernel<<<GIOU_GRID, GIOU_THREADS, 0, stream>>>(pred, targ, partials, n);
    giou_final_kernel<<<1, GIOU_THREADS, 0, stream>>>(partials, out, GIOU_GRID, n);
}